// Round 5
// baseline (1346.387 us; speedup 1.0000x reference)
//
#include <hip/hip_runtime.h>

#define N_NODES 100000
#define N_FEAT  1433
#define KP      1472     // padded K: 46*32
#define KLOOP   1440     // covers 0..1439 >= 1433 (15*96)
#define HID     64
#define NCLS    7

typedef __attribute__((ext_vector_type(8))) short short8v;
typedef __attribute__((ext_vector_type(4))) float f32x4;

__device__ __forceinline__ unsigned short f2bf(float v) {
    unsigned u = __float_as_uint(v);
    unsigned r = (u + 0x7FFFu + ((u >> 16) & 1u)) >> 16;   // RNE
    return (unsigned short)r;
}
__device__ __forceinline__ float bf2f(unsigned short h) {
    return __uint_as_float(((unsigned)h) << 16);
}

// ---------------- degree histogram ----------------
__global__ __launch_bounds__(256)
void hist_kernel(const int* __restrict__ dst, int* __restrict__ counts, int E) {
    int e = blockIdx.x * 256 + threadIdx.x;
    if (e < E) atomicAdd(&counts[dst[e]], 1);
}

__global__ __launch_bounds__(256)
void dinv_kernel(const int* __restrict__ counts, float* __restrict__ dinv, int n) {
    int i = blockIdx.x * 256 + threadIdx.x;
    if (i < n) dinv[i] = rsqrtf((float)(counts[i] + 1));   // +1 = self loop
}

// ---------------- single-block exclusive scan ----------------
__global__ __launch_bounds__(1024)
void scan_kernel(const int* __restrict__ counts, int* __restrict__ offsets,
                 int* __restrict__ cursor, int n) {
    __shared__ int sums[1024];
    int t = threadIdx.x;
    int chunk = (n + 1023) >> 10;
    int beg = t * chunk;
    int end = min(beg + chunk, n);
    int s = 0;
    for (int i = beg; i < end; ++i) s += counts[i];
    sums[t] = s;
    __syncthreads();
    for (int off = 1; off < 1024; off <<= 1) {
        int v = (t >= off) ? sums[t - off] : 0;
        __syncthreads();
        sums[t] += v;
        __syncthreads();
    }
    int run = (t == 0) ? 0 : sums[t - 1];
    for (int i = beg; i < end; ++i) {
        offsets[i] = run; cursor[i] = run;
        run += counts[i];
    }
    if (t == 1023) offsets[n] = run;
}

// ---------------- CSR scatter ----------------
__global__ __launch_bounds__(256)
void scatter_kernel(const int* __restrict__ src, const int* __restrict__ dst,
                    const float* __restrict__ dinv, int* __restrict__ cursor,
                    int* __restrict__ csr_src, float* __restrict__ csr_w, int E) {
    int e = blockIdx.x * 256 + threadIdx.x;
    if (e >= E) return;
    int s = src[e], d = dst[e];
    int pos = atomicAdd(&cursor[d], 1);
    csr_src[pos] = s;
    csr_w[pos]   = dinv[s] * dinv[d];
}

// ---------------- W1 transpose + bf16 hi/lo split: [1433,64] -> [64,KP] ----------------
__global__ __launch_bounds__(256)
void convert_w(const float* __restrict__ W,
               unsigned short* __restrict__ wt_hi, unsigned short* __restrict__ wt_lo) {
    int idx = blockIdx.x * 256 + threadIdx.x;   // over KP*64
    if (idx >= KP * 64) return;
    int k = idx >> 6, n = idx & 63;
    float v = (k < N_FEAT) ? W[(size_t)k * 64 + n] : 0.f;
    unsigned short h = f2bf(v);
    wt_hi[(size_t)n * KP + k] = h;
    wt_lo[(size_t)n * KP + k] = f2bf(v - bf2f(h));
}

// load 8 f32 from a (4B-aligned) row, convert to bf16 fragment
__device__ __forceinline__ short8v load_frag_f32(const float* __restrict__ row, int kk) {
    short8v r;
    if (kk + 8 <= N_FEAT) {
        float v[8];
        __builtin_memcpy(v, row + kk, 32);   // align-4 vector load
#pragma unroll
        for (int j = 0; j < 8; ++j) r[j] = (short)f2bf(v[j]);
    } else {
#pragma unroll
        for (int j = 0; j < 8; ++j)
            r[j] = (short)((kk + j < N_FEAT) ? f2bf(row[kk + j]) : (unsigned short)0);
    }
    return r;
}

// ---------------- GEMM1 v5: 64 rows/block (wave=16 rows) for occupancy ----------------
// A: X f32 direct, in-register bf16 convert. B direct from L2-resident wt hi/lo.
// No LDS, no barriers. Grid 1563 blocks -> ~6 blocks/CU -> 24 waves/CU.
__global__ __launch_bounds__(256)
void gemm_xw_v5(const float* __restrict__ X,
                const unsigned short* __restrict__ wt_hi,
                const unsigned short* __restrict__ wt_lo,
                unsigned short* __restrict__ H16, int M) {
    const int t    = threadIdx.x;
    const int lane = t & 63;
    const int w    = t >> 6;
    const int m0   = blockIdx.x * 64 + w * 16;
    const int lrow = lane & 15;
    const int koff = (lane >> 4) * 8;

    f32x4 acc[4];
#pragma unroll
    for (int j = 0; j < 4; ++j) acc[j] = (f32x4){0.f, 0.f, 0.f, 0.f};

    const float* a0 = X + (size_t)min(m0 + lrow, M - 1) * N_FEAT;
    const unsigned short* bh = wt_hi + (size_t)lrow * KP + koff;
    const unsigned short* bl = wt_lo + (size_t)lrow * KP + koff;

#pragma unroll 3
    for (int k = 0; k < KLOOP; k += 32) {
        int kk = k + koff;
        short8v aH, bH[4], bL[4];
        aH = load_frag_f32(a0, kk);
#pragma unroll
        for (int nf = 0; nf < 4; ++nf) {
            bH[nf] = *(const short8v*)(bh + (size_t)nf * 16 * KP + k);
            bL[nf] = *(const short8v*)(bl + (size_t)nf * 16 * KP + k);
        }
#pragma unroll
        for (int nf = 0; nf < 4; ++nf) {
            acc[nf] = __builtin_amdgcn_mfma_f32_16x16x32_bf16(aH, bH[nf], acc[nf], 0, 0, 0);
            acc[nf] = __builtin_amdgcn_mfma_f32_16x16x32_bf16(aH, bL[nf], acc[nf], 0, 0, 0);
        }
    }
    // C: col = lane&15, row = (lane>>4)*4 + reg
#pragma unroll
    for (int r = 0; r < 4; ++r) {
        int row = m0 + ((lane >> 4) << 2) + r;
        if (row < M) {
#pragma unroll
            for (int nf = 0; nf < 4; ++nf)
                H16[(size_t)row * 64 + nf * 16 + lrow] = f2bf(acc[nf][r]);
        }
    }
}

// ---------------- GEMM2: [M,64] f32 @ [64,64] via MFMA, W in swizzled LDS ----------------
__global__ __launch_bounds__(256)
void gemm_hid(const float* __restrict__ A, const float* __restrict__ W,
              unsigned short* __restrict__ H16, int M) {
    __shared__ __align__(16) unsigned short WsH[64 * 64];
    __shared__ __align__(16) unsigned short WsL[64 * 64];
    char* wsH = (char*)WsH; char* wsL = (char*)WsL;
    const int t = threadIdx.x;
#pragma unroll
    for (int p = 0; p < 16; ++p) {
        int id = p * 256 + t;           // 0..4095
        int k = id >> 6, n = id & 63;
        float v = W[id];
        unsigned short h = f2bf(v);
        int byte = (n * 128 + k * 2) ^ ((n & 7) << 4);
        *(unsigned short*)(wsH + byte) = h;
        *(unsigned short*)(wsL + byte) = f2bf(v - bf2f(h));
    }
    __syncthreads();

    const int lane = t & 63;
    const int w    = t >> 6;
    const int m0   = blockIdx.x * 64 + w * 16;
    const int lrow = lane & 15;
    const int koff = (lane >> 4) * 8;

    const float* a0 = A + (size_t)min(m0 + lrow, M - 1) * 64;

    f32x4 acc[4];
#pragma unroll
    for (int j = 0; j < 4; ++j) acc[j] = (f32x4){0.f, 0.f, 0.f, 0.f};

#pragma unroll
    for (int k = 0; k < 64; k += 32) {
        int kk = k + koff;
        short8v aH, bH[4], bL[4];
        float v0[8];
        __builtin_memcpy(v0, a0 + kk, 32);   // rows are 256B-aligned
#pragma unroll
        for (int j = 0; j < 8; ++j) aH[j] = (short)f2bf(v0[j]);
#pragma unroll
        for (int nf = 0; nf < 4; ++nf) {
            int n = nf * 16 + lrow;
            int byte = (n * 128 + kk * 2) ^ ((n & 7) << 4);
            bH[nf] = *(const short8v*)(wsH + byte);
            bL[nf] = *(const short8v*)(wsL + byte);
        }
#pragma unroll
        for (int nf = 0; nf < 4; ++nf) {
            acc[nf] = __builtin_amdgcn_mfma_f32_16x16x32_bf16(aH, bH[nf], acc[nf], 0, 0, 0);
            acc[nf] = __builtin_amdgcn_mfma_f32_16x16x32_bf16(aH, bL[nf], acc[nf], 0, 0, 0);
        }
    }
#pragma unroll
    for (int r = 0; r < 4; ++r) {
        int row = m0 + ((lane >> 4) << 2) + r;
        if (row < M) {
#pragma unroll
            for (int nf = 0; nf < 4; ++nf)
                H16[(size_t)row * 64 + nf * 16 + lrow] = f2bf(acc[nf][r]);
        }
    }
}

// ---------------- gather-aggregate: bf16 h, one wave per node, 8-deep pipeline ----------------
__global__ __launch_bounds__(256)
void aggregate_kernel(const unsigned short* __restrict__ h16, const int* __restrict__ csr_src,
                      const float* __restrict__ csr_w, const int* __restrict__ offsets,
                      const float* __restrict__ dinv, const float* __restrict__ bias,
                      float* __restrict__ out, int n) {
    int wave = (blockIdx.x * blockDim.x + threadIdx.x) >> 6;
    int lane = threadIdx.x & 63;
    if (wave >= n) return;
    float di  = dinv[wave];
    float acc = bf2f(h16[(size_t)wave * HID + lane]) * di * di;   // self loop
    int e = offsets[wave], end = offsets[wave + 1];
    for (; e + 8 <= end; e += 8) {
        int   s[8]; float wgt[8]; float hv[8];
#pragma unroll
        for (int j = 0; j < 8; ++j) { s[j] = csr_src[e + j]; wgt[j] = csr_w[e + j]; }
#pragma unroll
        for (int j = 0; j < 8; ++j) hv[j] = bf2f(h16[(size_t)s[j] * HID + lane]);
#pragma unroll
        for (int j = 0; j < 8; ++j) acc = fmaf(hv[j], wgt[j], acc);
    }
    for (; e < end; ++e)
        acc = fmaf(bf2f(h16[(size_t)csr_src[e] * HID + lane]), csr_w[e], acc);
    out[(size_t)wave * HID + lane] = fmaxf(acc + bias[lane], 0.f);
}

// ---------------- fused MLP head + log_softmax: wave handles 8 nodes ----------------
__global__ __launch_bounds__(256)
void mlp_kernel(const float* __restrict__ y,
                const float* __restrict__ Wf1, const float* __restrict__ bf1,
                const float* __restrict__ Wf2, const float* __restrict__ bf2,
                const float* __restrict__ Wf3, const float* __restrict__ bf3,
                float* __restrict__ out, int M) {
    __shared__ float W1s[64 * 64];
    __shared__ float W2s[64 * 64];
    __shared__ float W3s[64 * NCLS];
    __shared__ float b1s[64], b2s[64], b3s[NCLS];
    __shared__ float vbuf[4][64];
    __shared__ float zbuf[4][8];
    int tid = threadIdx.x;
    for (int i = tid; i < 4096; i += 256) { W1s[i] = Wf1[i]; W2s[i] = Wf2[i]; }
    for (int i = tid; i < 64 * NCLS; i += 256) W3s[i] = Wf3[i];
    if (tid < 64) { b1s[tid] = bf1[tid]; b2s[tid] = bf2[tid]; }
    if (tid < NCLS) b3s[tid] = bf3[tid];
    __syncthreads();
    int w = tid >> 6, lane = tid & 63;

    for (int it = 0; it < 8; ++it) {
        int node = blockIdx.x * 32 + w * 8 + it;
        if (node >= M) return;

        vbuf[w][lane] = y[(size_t)node * 64 + lane];
        float u = b1s[lane];
#pragma unroll
        for (int k = 0; k < 64; ++k) u = fmaf(vbuf[w][k], W1s[k * 64 + lane], u);
        u = fmaxf(u, 0.f);
        vbuf[w][lane] = u;
        float u2 = b2s[lane];
#pragma unroll
        for (int k = 0; k < 64; ++k) u2 = fmaf(vbuf[w][k], W2s[k * 64 + lane], u2);
        u2 = fmaxf(u2, 0.f);
        vbuf[w][lane] = u2;
        float z = 0.f;
        if (lane < NCLS) {
            z = b3s[lane];
#pragma unroll
            for (int k = 0; k < 64; ++k) z = fmaf(vbuf[w][k], W3s[k * NCLS + lane], z);
        }
        if (lane < 8)    zbuf[w][lane] = -1e30f;
        if (lane < NCLS) zbuf[w][lane] = z;
        float m = -1e30f;
#pragma unroll
        for (int j = 0; j < NCLS; ++j) m = fmaxf(m, zbuf[w][j]);
        float ssum = 0.f;
#pragma unroll
        for (int j = 0; j < NCLS; ++j) ssum += expf(zbuf[w][j] - m);
        float lse = m + logf(ssum);
        if (lane < NCLS) out[(size_t)node * NCLS + lane] = z - lse;
    }
}

extern "C" void kernel_launch(void* const* d_in, const int* in_sizes, int n_in,
                              void* d_out, int out_size, void* d_ws, size_t ws_size,
                              hipStream_t stream) {
    const float* x   = (const float*)d_in[0];
    const int*   ei  = (const int*)d_in[1];
    const float* W1  = (const float*)d_in[2];
    const float* b1  = (const float*)d_in[3];
    const float* W2  = (const float*)d_in[4];
    const float* b2  = (const float*)d_in[5];
    const float* Wf1 = (const float*)d_in[6];
    const float* bf1 = (const float*)d_in[7];
    const float* Wf2 = (const float*)d_in[8];
    const float* bf2 = (const float*)d_in[9];
    const float* Wf3 = (const float*)d_in[10];
    const float* bf3 = (const float*)d_in[11];

    const int N = N_NODES;
    const int E = in_sizes[1] / 2;
    float* outp = (float*)d_out;

    char* p = (char*)d_ws;
    auto alloc = [&](size_t bytes) {
        char* q = p;
        p += (bytes + 255) & ~(size_t)255;
        return q;
    };
    int*            counts  = (int*)           alloc((size_t)N * 4);
    int*            offsets = (int*)           alloc((size_t)(N + 1) * 4);
    int*            cursor  = (int*)           alloc((size_t)N * 4);
    float*          dinv    = (float*)         alloc((size_t)N * 4);
    int*            csr_src = (int*)           alloc((size_t)E * 4);
    float*          csr_w   = (float*)         alloc((size_t)E * 4);
    unsigned short* wt_hi   = (unsigned short*)alloc((size_t)64 * KP * 2);
    unsigned short* wt_lo   = (unsigned short*)alloc((size_t)64 * KP * 2);
    unsigned short* bufH16  = (unsigned short*)alloc((size_t)N * HID * 2);
    float*          bufF    = (float*)         alloc((size_t)N * HID * 4);

    const int* src = ei;
    const int* dst = ei + E;

    hipMemsetAsync(counts, 0, (size_t)N * 4, stream);
    int ge = (E + 255) / 256;
    hist_kernel<<<ge, 256, 0, stream>>>(dst, counts, E);
    dinv_kernel<<<(N + 255) / 256, 256, 0, stream>>>(counts, dinv, N);
    scan_kernel<<<1, 1024, 0, stream>>>(counts, offsets, cursor, N);
    scatter_kernel<<<ge, 256, 0, stream>>>(src, dst, dinv, cursor, csr_src, csr_w, E);
    convert_w<<<(KP * 64 + 255) / 256, 256, 0, stream>>>(W1, wt_hi, wt_lo);

    // layer 1
    gemm_xw_v5<<<(N + 63) / 64, 256, 0, stream>>>(x, wt_hi, wt_lo, bufH16, N);
    aggregate_kernel<<<(N + 3) / 4, 256, 0, stream>>>(bufH16, csr_src, csr_w, offsets, dinv, b1, bufF, N);
    // layer 2
    gemm_hid<<<(N + 63) / 64, 256, 0, stream>>>(bufF, W2, bufH16, N);
    aggregate_kernel<<<(N + 3) / 4, 256, 0, stream>>>(bufH16, csr_src, csr_w, offsets, dinv, b2, bufF, N);
    // head
    mlp_kernel<<<(N + 31) / 32, 256, 0, stream>>>(bufF, Wf1, bf1, Wf2, bf2, Wf3, bf3, outp, N);
}

// Round 6
// 1169.581 us; speedup vs baseline: 1.1512x; 1.1512x over previous
//
#include <hip/hip_runtime.h>

#define N_NODES 100000
#define N_FEAT  1433
#define KP      1472     // padded K: 46*32
#define NKT     46       // k-tiles of 32
#define HID     64
#define NCLS    7

typedef __attribute__((ext_vector_type(8))) short short8v;
typedef __attribute__((ext_vector_type(4))) float f32x4;

__device__ __forceinline__ unsigned short f2bf(float v) {
    unsigned u = __float_as_uint(v);
    unsigned r = (u + 0x7FFFu + ((u >> 16) & 1u)) >> 16;   // RNE
    return (unsigned short)r;
}
__device__ __forceinline__ float bf2f(unsigned short h) {
    return __uint_as_float(((unsigned)h) << 16);
}

// ---------------- degree histogram ----------------
__global__ __launch_bounds__(256)
void hist_kernel(const int* __restrict__ dst, int* __restrict__ counts, int E) {
    int e = blockIdx.x * 256 + threadIdx.x;
    if (e < E) atomicAdd(&counts[dst[e]], 1);
}

__global__ __launch_bounds__(256)
void dinv_kernel(const int* __restrict__ counts, float* __restrict__ dinv, int n) {
    int i = blockIdx.x * 256 + threadIdx.x;
    if (i < n) dinv[i] = rsqrtf((float)(counts[i] + 1));   // +1 = self loop
}

// ---------------- single-block exclusive scan ----------------
__global__ __launch_bounds__(1024)
void scan_kernel(const int* __restrict__ counts, int* __restrict__ offsets,
                 int* __restrict__ cursor, int n) {
    __shared__ int sums[1024];
    int t = threadIdx.x;
    int chunk = (n + 1023) >> 10;
    int beg = t * chunk;
    int end = min(beg + chunk, n);
    int s = 0;
    for (int i = beg; i < end; ++i) s += counts[i];
    sums[t] = s;
    __syncthreads();
    for (int off = 1; off < 1024; off <<= 1) {
        int v = (t >= off) ? sums[t - off] : 0;
        __syncthreads();
        sums[t] += v;
        __syncthreads();
    }
    int run = (t == 0) ? 0 : sums[t - 1];
    for (int i = beg; i < end; ++i) {
        offsets[i] = run; cursor[i] = run;
        run += counts[i];
    }
    if (t == 1023) offsets[n] = run;
}

// ---------------- CSR scatter ----------------
__global__ __launch_bounds__(256)
void scatter_kernel(const int* __restrict__ src, const int* __restrict__ dst,
                    const float* __restrict__ dinv, int* __restrict__ cursor,
                    int* __restrict__ csr_src, float* __restrict__ csr_w, int E) {
    int e = blockIdx.x * 256 + threadIdx.x;
    if (e >= E) return;
    int s = src[e], d = dst[e];
    int pos = atomicAdd(&cursor[d], 1);
    csr_src[pos] = s;
    csr_w[pos]   = dinv[s] * dinv[d];
}

// ---------------- W1 -> fragment-major bf16 hi/lo ----------------
// wf[(kt*4 + nf)*64 + lane] is a 16B fragment: elem j = W[kt*32+(lane>>4)*8+j][nf*16+(lane&15)]
// A B-load instruction then reads 64 lanes x 16B CONSECUTIVE (1KB contiguous).
__global__ __launch_bounds__(256)
void convert_wfrag(const float* __restrict__ W,
                   unsigned short* __restrict__ wfh, unsigned short* __restrict__ wfl) {
    int tid = blockIdx.x * 256 + threadIdx.x;   // over NKT*4*64 = 11776 fragments
    if (tid >= NKT * 4 * 64) return;
    int kt   = tid >> 8;
    int rem  = tid & 255;
    int nf   = rem >> 6;
    int lane = rem & 63;
    int n  = nf * 16 + (lane & 15);
    int kb = kt * 32 + ((lane >> 4) << 3);
    short8v hi, lo;
#pragma unroll
    for (int j = 0; j < 8; ++j) {
        int k = kb + j;
        float v = (k < N_FEAT) ? W[(size_t)k * 64 + n] : 0.f;
        unsigned short h = f2bf(v);
        hi[j] = (short)h;
        lo[j] = (short)f2bf(v - bf2f(h));
    }
    *(short8v*)(wfh + (size_t)tid * 8) = hi;
    *(short8v*)(wfl + (size_t)tid * 8) = lo;
}

// load 8 f32 from a (4B-aligned) row, convert to bf16 fragment (masked tail path)
__device__ __forceinline__ short8v load_frag_f32(const float* __restrict__ row, int kk) {
    short8v r;
    if (kk + 8 <= N_FEAT) {
        float v[8];
        __builtin_memcpy(v, row + kk, 32);
#pragma unroll
        for (int j = 0; j < 8; ++j) r[j] = (short)f2bf(v[j]);
    } else {
#pragma unroll
        for (int j = 0; j < 8; ++j)
            r[j] = (short)((kk + j < N_FEAT) ? f2bf(row[kk + j]) : (unsigned short)0);
    }
    return r;
}

// ---------------- GEMM1 v6: 32 rows/wave, fragment-major B, branch-free main loop ----------------
__global__ __launch_bounds__(256)
void gemm_xw_v6(const float* __restrict__ X,
                const unsigned short* __restrict__ wfh,
                const unsigned short* __restrict__ wfl,
                unsigned short* __restrict__ H16, int M) {
    const int t    = threadIdx.x;
    const int lane = t & 63;
    const int w    = t >> 6;
    const int m0   = blockIdx.x * 128 + w * 32;
    const int lrow = lane & 15;
    const int koff = (lane >> 4) * 8;

    f32x4 acc[2][4];
#pragma unroll
    for (int i = 0; i < 2; ++i)
#pragma unroll
        for (int j = 0; j < 4; ++j) acc[i][j] = (f32x4){0.f, 0.f, 0.f, 0.f};

    const float* a0 = X + (size_t)min(m0 + lrow,      M - 1) * N_FEAT;
    const float* a1 = X + (size_t)min(m0 + 16 + lrow, M - 1) * N_FEAT;
    const short8v* bh = (const short8v*)wfh + lane;   // + (kt*4+nf)*64
    const short8v* bl = (const short8v*)wfl + lane;

    // main loop: kt = 0..43, max read = 43*32+24+8 = 1408 <= N_FEAT -> branch-free
#pragma unroll 4
    for (int kt = 0; kt < 44; ++kt) {
        int kk = kt * 32 + koff;
        short8v aH[2], bH[4], bL[4];
        float v0[8], v1[8];
        __builtin_memcpy(v0, a0 + kk, 32);
        __builtin_memcpy(v1, a1 + kk, 32);
#pragma unroll
        for (int j = 0; j < 8; ++j) {
            aH[0][j] = (short)f2bf(v0[j]);
            aH[1][j] = (short)f2bf(v1[j]);
        }
#pragma unroll
        for (int nf = 0; nf < 4; ++nf) {
            bH[nf] = bh[(kt * 4 + nf) * 64];
            bL[nf] = bl[(kt * 4 + nf) * 64];
        }
#pragma unroll
        for (int mf = 0; mf < 2; ++mf)
#pragma unroll
            for (int nf = 0; nf < 4; ++nf) {
                acc[mf][nf] = __builtin_amdgcn_mfma_f32_16x16x32_bf16(aH[mf], bH[nf], acc[mf][nf], 0, 0, 0);
                acc[mf][nf] = __builtin_amdgcn_mfma_f32_16x16x32_bf16(aH[mf], bL[nf], acc[mf][nf], 0, 0, 0);
            }
    }
    // tail: kt = 44 (k 1408..1439, masked >= 1433)
    {
        const int kt = 44;
        int kk = kt * 32 + koff;
        short8v aH[2], bH[4], bL[4];
        aH[0] = load_frag_f32(a0, kk);
        aH[1] = load_frag_f32(a1, kk);
#pragma unroll
        for (int nf = 0; nf < 4; ++nf) {
            bH[nf] = bh[(kt * 4 + nf) * 64];
            bL[nf] = bl[(kt * 4 + nf) * 64];
        }
#pragma unroll
        for (int mf = 0; mf < 2; ++mf)
#pragma unroll
            for (int nf = 0; nf < 4; ++nf) {
                acc[mf][nf] = __builtin_amdgcn_mfma_f32_16x16x32_bf16(aH[mf], bH[nf], acc[mf][nf], 0, 0, 0);
                acc[mf][nf] = __builtin_amdgcn_mfma_f32_16x16x32_bf16(aH[mf], bL[nf], acc[mf][nf], 0, 0, 0);
            }
    }
    // C: col = lane&15, row = (lane>>4)*4 + reg
#pragma unroll
    for (int mf = 0; mf < 2; ++mf)
#pragma unroll
        for (int r = 0; r < 4; ++r) {
            int row = m0 + mf * 16 + ((lane >> 4) << 2) + r;
            if (row < M) {
#pragma unroll
                for (int nf = 0; nf < 4; ++nf)
                    H16[(size_t)row * 64 + nf * 16 + lrow] = f2bf(acc[mf][nf][r]);
            }
        }
}

// ---------------- GEMM2: [M,64] f32 @ [64,64] via MFMA, W in swizzled LDS ----------------
__global__ __launch_bounds__(256)
void gemm_hid(const float* __restrict__ A, const float* __restrict__ W,
              unsigned short* __restrict__ H16, int M) {
    __shared__ __align__(16) unsigned short WsH[64 * 64];
    __shared__ __align__(16) unsigned short WsL[64 * 64];
    char* wsH = (char*)WsH; char* wsL = (char*)WsL;
    const int t = threadIdx.x;
#pragma unroll
    for (int p = 0; p < 16; ++p) {
        int id = p * 256 + t;           // 0..4095
        int k = id >> 6, n = id & 63;
        float v = W[id];
        unsigned short h = f2bf(v);
        int byte = (n * 128 + k * 2) ^ ((n & 7) << 4);
        *(unsigned short*)(wsH + byte) = h;
        *(unsigned short*)(wsL + byte) = f2bf(v - bf2f(h));
    }
    __syncthreads();

    const int lane = t & 63;
    const int w    = t >> 6;
    const int m0   = blockIdx.x * 64 + w * 16;
    const int lrow = lane & 15;
    const int koff = (lane >> 4) * 8;

    const float* a0 = A + (size_t)min(m0 + lrow, M - 1) * 64;

    f32x4 acc[4];
#pragma unroll
    for (int j = 0; j < 4; ++j) acc[j] = (f32x4){0.f, 0.f, 0.f, 0.f};

#pragma unroll
    for (int k = 0; k < 64; k += 32) {
        int kk = k + koff;
        short8v aH, bH[4], bL[4];
        float v0[8];
        __builtin_memcpy(v0, a0 + kk, 32);   // rows are 256B-aligned
#pragma unroll
        for (int j = 0; j < 8; ++j) aH[j] = (short)f2bf(v0[j]);
#pragma unroll
        for (int nf = 0; nf < 4; ++nf) {
            int n = nf * 16 + lrow;
            int byte = (n * 128 + kk * 2) ^ ((n & 7) << 4);
            bH[nf] = *(const short8v*)(wsH + byte);
            bL[nf] = *(const short8v*)(wsL + byte);
        }
#pragma unroll
        for (int nf = 0; nf < 4; ++nf) {
            acc[nf] = __builtin_amdgcn_mfma_f32_16x16x32_bf16(aH, bH[nf], acc[nf], 0, 0, 0);
            acc[nf] = __builtin_amdgcn_mfma_f32_16x16x32_bf16(aH, bL[nf], acc[nf], 0, 0, 0);
        }
    }
#pragma unroll
    for (int r = 0; r < 4; ++r) {
        int row = m0 + ((lane >> 4) << 2) + r;
        if (row < M) {
#pragma unroll
            for (int nf = 0; nf < 4; ++nf)
                H16[(size_t)row * 64 + nf * 16 + lrow] = f2bf(acc[nf][r]);
        }
    }
}

// ---------------- gather-aggregate: bf16 h, one wave per node, 8-deep pipeline ----------------
__global__ __launch_bounds__(256)
void aggregate_kernel(const unsigned short* __restrict__ h16, const int* __restrict__ csr_src,
                      const float* __restrict__ csr_w, const int* __restrict__ offsets,
                      const float* __restrict__ dinv, const float* __restrict__ bias,
                      float* __restrict__ out, int n) {
    int wave = (blockIdx.x * blockDim.x + threadIdx.x) >> 6;
    int lane = threadIdx.x & 63;
    if (wave >= n) return;
    float di  = dinv[wave];
    float acc = bf2f(h16[(size_t)wave * HID + lane]) * di * di;   // self loop
    int e = offsets[wave], end = offsets[wave + 1];
    for (; e + 8 <= end; e += 8) {
        int   s[8]; float wgt[8]; float hv[8];
#pragma unroll
        for (int j = 0; j < 8; ++j) { s[j] = csr_src[e + j]; wgt[j] = csr_w[e + j]; }
#pragma unroll
        for (int j = 0; j < 8; ++j) hv[j] = bf2f(h16[(size_t)s[j] * HID + lane]);
#pragma unroll
        for (int j = 0; j < 8; ++j) acc = fmaf(hv[j], wgt[j], acc);
    }
    for (; e < end; ++e)
        acc = fmaf(bf2f(h16[(size_t)csr_src[e] * HID + lane]), csr_w[e], acc);
    out[(size_t)wave * HID + lane] = fmaxf(acc + bias[lane], 0.f);
}

// ---------------- fused MLP head + log_softmax: wave handles 8 nodes ----------------
__global__ __launch_bounds__(256)
void mlp_kernel(const float* __restrict__ y,
                const float* __restrict__ Wf1, const float* __restrict__ bf1,
                const float* __restrict__ Wf2, const float* __restrict__ bf2,
                const float* __restrict__ Wf3, const float* __restrict__ bf3,
                float* __restrict__ out, int M) {
    __shared__ float W1s[64 * 64];
    __shared__ float W2s[64 * 64];
    __shared__ float W3s[64 * NCLS];
    __shared__ float b1s[64], b2s[64], b3s[NCLS];
    __shared__ float vbuf[4][64];
    __shared__ float zbuf[4][8];
    int tid = threadIdx.x;
    for (int i = tid; i < 4096; i += 256) { W1s[i] = Wf1[i]; W2s[i] = Wf2[i]; }
    for (int i = tid; i < 64 * NCLS; i += 256) W3s[i] = Wf3[i];
    if (tid < 64) { b1s[tid] = bf1[tid]; b2s[tid] = bf2[tid]; }
    if (tid < NCLS) b3s[tid] = bf3[tid];
    __syncthreads();
    int w = tid >> 6, lane = tid & 63;

    for (int it = 0; it < 8; ++it) {
        int node = blockIdx.x * 32 + w * 8 + it;
        if (node >= M) return;

        vbuf[w][lane] = y[(size_t)node * 64 + lane];
        float u = b1s[lane];
#pragma unroll
        for (int k = 0; k < 64; ++k) u = fmaf(vbuf[w][k], W1s[k * 64 + lane], u);
        u = fmaxf(u, 0.f);
        vbuf[w][lane] = u;
        float u2 = b2s[lane];
#pragma unroll
        for (int k = 0; k < 64; ++k) u2 = fmaf(vbuf[w][k], W2s[k * 64 + lane], u2);
        u2 = fmaxf(u2, 0.f);
        vbuf[w][lane] = u2;
        float z = 0.f;
        if (lane < NCLS) {
            z = b3s[lane];
#pragma unroll
            for (int k = 0; k < 64; ++k) z = fmaf(vbuf[w][k], W3s[k * NCLS + lane], z);
        }
        if (lane < 8)    zbuf[w][lane] = -1e30f;
        if (lane < NCLS) zbuf[w][lane] = z;
        float m = -1e30f;
#pragma unroll
        for (int j = 0; j < NCLS; ++j) m = fmaxf(m, zbuf[w][j]);
        float ssum = 0.f;
#pragma unroll
        for (int j = 0; j < NCLS; ++j) ssum += expf(zbuf[w][j] - m);
        float lse = m + logf(ssum);
        if (lane < NCLS) out[(size_t)node * NCLS + lane] = z - lse;
    }
}

extern "C" void kernel_launch(void* const* d_in, const int* in_sizes, int n_in,
                              void* d_out, int out_size, void* d_ws, size_t ws_size,
                              hipStream_t stream) {
    const float* x   = (const float*)d_in[0];
    const int*   ei  = (const int*)d_in[1];
    const float* W1  = (const float*)d_in[2];
    const float* b1  = (const float*)d_in[3];
    const float* W2  = (const float*)d_in[4];
    const float* b2  = (const float*)d_in[5];
    const float* Wf1 = (const float*)d_in[6];
    const float* bf1 = (const float*)d_in[7];
    const float* Wf2 = (const float*)d_in[8];
    const float* bf2 = (const float*)d_in[9];
    const float* Wf3 = (const float*)d_in[10];
    const float* bf3 = (const float*)d_in[11];

    const int N = N_NODES;
    const int E = in_sizes[1] / 2;
    float* outp = (float*)d_out;

    char* p = (char*)d_ws;
    auto alloc = [&](size_t bytes) {
        char* q = p;
        p += (bytes + 255) & ~(size_t)255;
        return q;
    };
    int*            counts  = (int*)           alloc((size_t)N * 4);
    int*            offsets = (int*)           alloc((size_t)(N + 1) * 4);
    int*            cursor  = (int*)           alloc((size_t)N * 4);
    float*          dinv    = (float*)         alloc((size_t)N * 4);
    int*            csr_src = (int*)           alloc((size_t)E * 4);
    float*          csr_w   = (float*)         alloc((size_t)E * 4);
    unsigned short* wfh     = (unsigned short*)alloc((size_t)NKT * 4 * 64 * 8 * 2);
    unsigned short* wfl     = (unsigned short*)alloc((size_t)NKT * 4 * 64 * 8 * 2);
    unsigned short* bufH16  = (unsigned short*)alloc((size_t)N * HID * 2);
    float*          bufF    = (float*)         alloc((size_t)N * HID * 4);

    const int* src = ei;
    const int* dst = ei + E;

    hipMemsetAsync(counts, 0, (size_t)N * 4, stream);
    int ge = (E + 255) / 256;
    hist_kernel<<<ge, 256, 0, stream>>>(dst, counts, E);
    dinv_kernel<<<(N + 255) / 256, 256, 0, stream>>>(counts, dinv, N);
    scan_kernel<<<1, 1024, 0, stream>>>(counts, offsets, cursor, N);
    scatter_kernel<<<ge, 256, 0, stream>>>(src, dst, dinv, cursor, csr_src, csr_w, E);
    convert_wfrag<<<(NKT * 4 * 64 + 255) / 256, 256, 0, stream>>>(W1, wfh, wfl);

    // layer 1
    gemm_xw_v6<<<(N + 127) / 128, 256, 0, stream>>>(x, wfh, wfl, bufH16, N);
    aggregate_kernel<<<(N + 3) / 4, 256, 0, stream>>>(bufH16, csr_src, csr_w, offsets, dinv, b1, bufF, N);
    // layer 2
    gemm_hid<<<(N + 63) / 64, 256, 0, stream>>>(bufF, W2, bufH16, N);
    aggregate_kernel<<<(N + 3) / 4, 256, 0, stream>>>(bufH16, csr_src, csr_w, offsets, dinv, b2, bufF, N);
    // head
    mlp_kernel<<<(N + 31) / 32, 256, 0, stream>>>(bufF, Wf1, bf1, Wf2, bf2, Wf3, bf3, outp, N);
}

// Round 7
// 1014.290 us; speedup vs baseline: 1.3274x; 1.1531x over previous
//
#include <hip/hip_runtime.h>

#define N_NODES 100000
#define N_FEAT  1433
#define NKT1    46       // k-tiles of 32 for K=1433->1472
#define HID     64
#define NCLS    7

typedef __attribute__((ext_vector_type(8))) short short8v;
typedef __attribute__((ext_vector_type(4))) float f32x4;

__device__ __forceinline__ unsigned short f2bf(float v) {
    unsigned u = __float_as_uint(v);
    unsigned r = (u + 0x7FFFu + ((u >> 16) & 1u)) >> 16;   // RNE
    return (unsigned short)r;
}
__device__ __forceinline__ float bf2f(unsigned short h) {
    return __uint_as_float(((unsigned)h) << 16);
}

// ---------------- degree histogram ----------------
__global__ __launch_bounds__(256)
void hist_kernel(const int* __restrict__ dst, int* __restrict__ counts, int E) {
    int e = blockIdx.x * 256 + threadIdx.x;
    if (e < E) atomicAdd(&counts[dst[e]], 1);
}

__global__ __launch_bounds__(256)
void dinv_kernel(const int* __restrict__ counts, float* __restrict__ dinv, int n) {
    int i = blockIdx.x * 256 + threadIdx.x;
    if (i < n) dinv[i] = rsqrtf((float)(counts[i] + 1));   // +1 = self loop
}

// ---------------- single-block exclusive scan ----------------
__global__ __launch_bounds__(1024)
void scan_kernel(const int* __restrict__ counts, int* __restrict__ offsets,
                 int* __restrict__ cursor, int n) {
    __shared__ int sums[1024];
    int t = threadIdx.x;
    int chunk = (n + 1023) >> 10;
    int beg = t * chunk;
    int end = min(beg + chunk, n);
    int s = 0;
    for (int i = beg; i < end; ++i) s += counts[i];
    sums[t] = s;
    __syncthreads();
    for (int off = 1; off < 1024; off <<= 1) {
        int v = (t >= off) ? sums[t - off] : 0;
        __syncthreads();
        sums[t] += v;
        __syncthreads();
    }
    int run = (t == 0) ? 0 : sums[t - 1];
    for (int i = beg; i < end; ++i) {
        offsets[i] = run; cursor[i] = run;
        run += counts[i];
    }
    if (t == 1023) offsets[n] = run;
}

// ---------------- CSR scatter ----------------
__global__ __launch_bounds__(256)
void scatter_kernel(const int* __restrict__ src, const int* __restrict__ dst,
                    const float* __restrict__ dinv, int* __restrict__ cursor,
                    int* __restrict__ csr_src, float* __restrict__ csr_w, int E) {
    int e = blockIdx.x * 256 + threadIdx.x;
    if (e >= E) return;
    int s = src[e], d = dst[e];
    int pos = atomicAdd(&cursor[d], 1);
    csr_src[pos] = s;
    csr_w[pos]   = dinv[s] * dinv[d];
}

// ---------------- generic W -> fragment-major bf16 hi/lo ----------------
// wf[(kt*nfc + nf)*64 + lane] fragment: elem j = W[kt*32+(lane>>4)*8+j][nf*16+(lane&15)]
__global__ __launch_bounds__(256)
void convert_wfrag_g(const float* __restrict__ W, int K, int ncols, int nkt, int nfc,
                     unsigned short* __restrict__ wfh, unsigned short* __restrict__ wfl) {
    int tid = blockIdx.x * 256 + threadIdx.x;
    if (tid >= nkt * nfc * 64) return;
    int kt   = tid / (nfc * 64);
    int rem  = tid % (nfc * 64);
    int nf   = rem >> 6;
    int lane = rem & 63;
    int n  = nf * 16 + (lane & 15);
    int kb = kt * 32 + ((lane >> 4) << 3);
    short8v hi, lo;
#pragma unroll
    for (int j = 0; j < 8; ++j) {
        int k = kb + j;
        float v = (k < K && n < ncols) ? W[(size_t)k * ncols + n] : 0.f;
        unsigned short h = f2bf(v);
        hi[j] = (short)h;
        lo[j] = (short)f2bf(v - bf2f(h));
    }
    *(short8v*)(wfh + (size_t)tid * 8) = hi;
    *(short8v*)(wfl + (size_t)tid * 8) = lo;
}

// load 8 f32 from a (4B-aligned) row, convert to bf16 fragment (masked tail path)
__device__ __forceinline__ short8v load_frag_f32(const float* __restrict__ row, int kk) {
    short8v r;
    if (kk + 8 <= N_FEAT) {
        float v[8];
        __builtin_memcpy(v, row + kk, 32);
#pragma unroll
        for (int j = 0; j < 8; ++j) r[j] = (short)f2bf(v[j]);
    } else {
#pragma unroll
        for (int j = 0; j < 8; ++j)
            r[j] = (short)((kk + j < N_FEAT) ? f2bf(row[kk + j]) : (unsigned short)0);
    }
    return r;
}

// ---------------- GEMM1 v6: 32 rows/wave, fragment-major B, branch-free main loop ----------------
__global__ __launch_bounds__(256)
void gemm_xw_v6(const float* __restrict__ X,
                const unsigned short* __restrict__ wfh,
                const unsigned short* __restrict__ wfl,
                unsigned short* __restrict__ H16, int M) {
    const int t    = threadIdx.x;
    const int lane = t & 63;
    const int w    = t >> 6;
    const int m0   = blockIdx.x * 128 + w * 32;
    const int lrow = lane & 15;
    const int koff = (lane >> 4) * 8;

    f32x4 acc[2][4];
#pragma unroll
    for (int i = 0; i < 2; ++i)
#pragma unroll
        for (int j = 0; j < 4; ++j) acc[i][j] = (f32x4){0.f, 0.f, 0.f, 0.f};

    const float* a0 = X + (size_t)min(m0 + lrow,      M - 1) * N_FEAT;
    const float* a1 = X + (size_t)min(m0 + 16 + lrow, M - 1) * N_FEAT;
    const short8v* bh = (const short8v*)wfh + lane;   // + (kt*4+nf)*64
    const short8v* bl = (const short8v*)wfl + lane;

#pragma unroll 4
    for (int kt = 0; kt < 44; ++kt) {
        int kk = kt * 32 + koff;
        short8v aH[2], bH[4], bL[4];
        float v0[8], v1[8];
        __builtin_memcpy(v0, a0 + kk, 32);
        __builtin_memcpy(v1, a1 + kk, 32);
#pragma unroll
        for (int j = 0; j < 8; ++j) {
            aH[0][j] = (short)f2bf(v0[j]);
            aH[1][j] = (short)f2bf(v1[j]);
        }
#pragma unroll
        for (int nf = 0; nf < 4; ++nf) {
            bH[nf] = bh[(kt * 4 + nf) * 64];
            bL[nf] = bl[(kt * 4 + nf) * 64];
        }
#pragma unroll
        for (int mf = 0; mf < 2; ++mf)
#pragma unroll
            for (int nf = 0; nf < 4; ++nf) {
                acc[mf][nf] = __builtin_amdgcn_mfma_f32_16x16x32_bf16(aH[mf], bH[nf], acc[mf][nf], 0, 0, 0);
                acc[mf][nf] = __builtin_amdgcn_mfma_f32_16x16x32_bf16(aH[mf], bL[nf], acc[mf][nf], 0, 0, 0);
            }
    }
    {   // tail kt=44 (k 1408..1439, masked >= 1433)
        const int kt = 44;
        int kk = kt * 32 + koff;
        short8v aH[2], bH[4], bL[4];
        aH[0] = load_frag_f32(a0, kk);
        aH[1] = load_frag_f32(a1, kk);
#pragma unroll
        for (int nf = 0; nf < 4; ++nf) {
            bH[nf] = bh[(kt * 4 + nf) * 64];
            bL[nf] = bl[(kt * 4 + nf) * 64];
        }
#pragma unroll
        for (int mf = 0; mf < 2; ++mf)
#pragma unroll
            for (int nf = 0; nf < 4; ++nf) {
                acc[mf][nf] = __builtin_amdgcn_mfma_f32_16x16x32_bf16(aH[mf], bH[nf], acc[mf][nf], 0, 0, 0);
                acc[mf][nf] = __builtin_amdgcn_mfma_f32_16x16x32_bf16(aH[mf], bL[nf], acc[mf][nf], 0, 0, 0);
            }
    }
#pragma unroll
    for (int mf = 0; mf < 2; ++mf)
#pragma unroll
        for (int r = 0; r < 4; ++r) {
            int row = m0 + mf * 16 + ((lane >> 4) << 2) + r;
            if (row < M) {
#pragma unroll
                for (int nf = 0; nf < 4; ++nf)
                    H16[(size_t)row * 64 + nf * 16 + lrow] = f2bf(acc[mf][nf][r]);
            }
        }
}

// ---------------- GEMM2 v2: [M,64] f32 @ [64,64], barrier-free, frag-major W2 ----------------
__global__ __launch_bounds__(256)
void gemm_hid_v2(const float* __restrict__ A,
                 const unsigned short* __restrict__ wfh,
                 const unsigned short* __restrict__ wfl,
                 unsigned short* __restrict__ H16, int M) {
    const int t    = threadIdx.x;
    const int lane = t & 63;
    const int w    = t >> 6;
    const int m0   = blockIdx.x * 128 + w * 32;
    const int lrow = lane & 15;
    const int koff = (lane >> 4) * 8;

    f32x4 acc[2][4];
#pragma unroll
    for (int i = 0; i < 2; ++i)
#pragma unroll
        for (int j = 0; j < 4; ++j) acc[i][j] = (f32x4){0.f, 0.f, 0.f, 0.f};

    const float* a0 = A + (size_t)min(m0 + lrow,      M - 1) * 64;
    const float* a1 = A + (size_t)min(m0 + 16 + lrow, M - 1) * 64;
    const short8v* bh = (const short8v*)wfh + lane;
    const short8v* bl = (const short8v*)wfl + lane;

#pragma unroll
    for (int kt = 0; kt < 2; ++kt) {
        int kk = kt * 32 + koff;
        short8v aH[2], bH[4], bL[4];
        float v0[8], v1[8];
        __builtin_memcpy(v0, a0 + kk, 32);   // rows 256B-aligned
        __builtin_memcpy(v1, a1 + kk, 32);
#pragma unroll
        for (int j = 0; j < 8; ++j) {
            aH[0][j] = (short)f2bf(v0[j]);
            aH[1][j] = (short)f2bf(v1[j]);
        }
#pragma unroll
        for (int nf = 0; nf < 4; ++nf) {
            bH[nf] = bh[(kt * 4 + nf) * 64];
            bL[nf] = bl[(kt * 4 + nf) * 64];
        }
#pragma unroll
        for (int mf = 0; mf < 2; ++mf)
#pragma unroll
            for (int nf = 0; nf < 4; ++nf) {
                acc[mf][nf] = __builtin_amdgcn_mfma_f32_16x16x32_bf16(aH[mf], bH[nf], acc[mf][nf], 0, 0, 0);
                acc[mf][nf] = __builtin_amdgcn_mfma_f32_16x16x32_bf16(aH[mf], bL[nf], acc[mf][nf], 0, 0, 0);
            }
    }
#pragma unroll
    for (int mf = 0; mf < 2; ++mf)
#pragma unroll
        for (int r = 0; r < 4; ++r) {
            int row = m0 + mf * 16 + ((lane >> 4) << 2) + r;
            if (row < M) {
#pragma unroll
                for (int nf = 0; nf < 4; ++nf)
                    H16[(size_t)row * 64 + nf * 16 + lrow] = f2bf(acc[mf][nf][r]);
            }
        }
}

// ---------------- aggregate v2: wave per node, 16-lane group per edge (4 edges/instr) ----------------
__global__ __launch_bounds__(256)
void aggregate_v2(const unsigned short* __restrict__ h16, const int* __restrict__ csr_src,
                  const float* __restrict__ csr_w, const int* __restrict__ offsets,
                  const float* __restrict__ dinv, const float* __restrict__ bias,
                  float* __restrict__ out, int n) {
    int wid  = (blockIdx.x * blockDim.x + threadIdx.x) >> 6;
    int lane = threadIdx.x & 63;
    if (wid >= n) return;
    const int g  = lane >> 4;          // edge subgroup 0..3
    const int f4 = (lane & 15) * 4;    // feature base

    float a0 = 0.f, a1 = 0.f, a2 = 0.f, a3 = 0.f;
    int beg = offsets[wid], end = offsets[wid + 1];
    int nq  = (end - beg) >> 2;
    int e   = beg + g;
#pragma unroll 2
    for (int q = 0; q < nq; ++q, e += 4) {
        int   s   = csr_src[e];
        float wgt = csr_w[e];
        ushort4 hv = *(const ushort4*)(h16 + (size_t)s * HID + f4);
        a0 = fmaf(bf2f(hv.x), wgt, a0);
        a1 = fmaf(bf2f(hv.y), wgt, a1);
        a2 = fmaf(bf2f(hv.z), wgt, a2);
        a3 = fmaf(bf2f(hv.w), wgt, a3);
    }
    int rem = (end - beg) & 3;
    if (g < rem) {
        int   s   = csr_src[e];
        float wgt = csr_w[e];
        ushort4 hv = *(const ushort4*)(h16 + (size_t)s * HID + f4);
        a0 = fmaf(bf2f(hv.x), wgt, a0);
        a1 = fmaf(bf2f(hv.y), wgt, a1);
        a2 = fmaf(bf2f(hv.z), wgt, a2);
        a3 = fmaf(bf2f(hv.w), wgt, a3);
    }
    if (g == 0) {   // self loop
        float di = dinv[wid];
        float w2 = di * di;
        ushort4 hv = *(const ushort4*)(h16 + (size_t)wid * HID + f4);
        a0 = fmaf(bf2f(hv.x), w2, a0);
        a1 = fmaf(bf2f(hv.y), w2, a1);
        a2 = fmaf(bf2f(hv.z), w2, a2);
        a3 = fmaf(bf2f(hv.w), w2, a3);
    }
    // reduce across 4 groups
    a0 += __shfl_xor(a0, 16); a0 += __shfl_xor(a0, 32);
    a1 += __shfl_xor(a1, 16); a1 += __shfl_xor(a1, 32);
    a2 += __shfl_xor(a2, 16); a2 += __shfl_xor(a2, 32);
    a3 += __shfl_xor(a3, 16); a3 += __shfl_xor(a3, 32);
    if (g == 0) {
        float4 bv = *(const float4*)&bias[f4];
        float4 o;
        o.x = fmaxf(a0 + bv.x, 0.f);
        o.y = fmaxf(a1 + bv.y, 0.f);
        o.z = fmaxf(a2 + bv.z, 0.f);
        o.w = fmaxf(a3 + bv.w, 0.f);
        *(float4*)&out[(size_t)wid * HID + f4] = o;
    }
}

// ---------------- fused MLP head via MFMA + butterfly log_softmax ----------------
__device__ __forceinline__ void split8(const float* v, short8v& h, short8v& l) {
#pragma unroll
    for (int j = 0; j < 8; ++j) {
        unsigned short hh = f2bf(v[j]);
        h[j] = (short)hh;
        l[j] = (short)f2bf(v[j] - bf2f(hh));
    }
}

__global__ __launch_bounds__(256)
void mlp_mfma(const float* __restrict__ y,
              const unsigned short* __restrict__ w1h, const unsigned short* __restrict__ w1l,
              const unsigned short* __restrict__ w2h, const unsigned short* __restrict__ w2l,
              const unsigned short* __restrict__ w3h, const unsigned short* __restrict__ w3l,
              const float* __restrict__ bf1, const float* __restrict__ bf2,
              const float* __restrict__ bf3,
              float* __restrict__ out, int M) {
    __shared__ float tbuf[4][32 * 64];
    const int t    = threadIdx.x;
    const int lane = t & 63;
    const int w    = t >> 6;
    const int m0   = blockIdx.x * 128 + w * 32;
    const int lrow = lane & 15;
    const int hi16 = lane >> 4;
    const int koff = hi16 * 8;
    float* tb = tbuf[w];

    float b1v[4], b2v[4];
#pragma unroll
    for (int nf = 0; nf < 4; ++nf) {
        b1v[nf] = bf1[nf * 16 + lrow];
        b2v[nf] = bf2[nf * 16 + lrow];
    }
    float b3v = (lrow < NCLS) ? bf3[lrow] : 0.f;

    // ---- A frags from y (f32) ----
    short8v aH[2][2], aL[2][2];   // [mf][kt]
    {
        const float* a0 = y + (size_t)min(m0 + lrow,      M - 1) * 64;
        const float* a1 = y + (size_t)min(m0 + 16 + lrow, M - 1) * 64;
#pragma unroll
        for (int kt = 0; kt < 2; ++kt) {
            float v0[8], v1[8];
            __builtin_memcpy(v0, a0 + kt * 32 + koff, 32);
            __builtin_memcpy(v1, a1 + kt * 32 + koff, 32);
            split8(v0, aH[0][kt], aL[0][kt]);
            split8(v1, aH[1][kt], aL[1][kt]);
        }
    }

    // ---- layer 1 & 2 (64x64, relu) ----
#pragma unroll
    for (int layer = 0; layer < 2; ++layer) {
        const unsigned short* wh = layer ? w2h : w1h;
        const unsigned short* wl = layer ? w2l : w1l;
        const float* bv = layer ? b2v : b1v;
        f32x4 acc[2][4];
#pragma unroll
        for (int i = 0; i < 2; ++i)
#pragma unroll
            for (int j = 0; j < 4; ++j) acc[i][j] = (f32x4){0.f, 0.f, 0.f, 0.f};
#pragma unroll
        for (int kt = 0; kt < 2; ++kt) {
            short8v bH[4], bL[4];
#pragma unroll
            for (int nf = 0; nf < 4; ++nf) {
                bH[nf] = *((const short8v*)wh + (kt * 4 + nf) * 64 + lane);
                bL[nf] = *((const short8v*)wl + (kt * 4 + nf) * 64 + lane);
            }
#pragma unroll
            for (int mf = 0; mf < 2; ++mf)
#pragma unroll
                for (int nf = 0; nf < 4; ++nf) {
                    acc[mf][nf] = __builtin_amdgcn_mfma_f32_16x16x32_bf16(aH[mf][kt], bH[nf], acc[mf][nf], 0, 0, 0);
                    acc[mf][nf] = __builtin_amdgcn_mfma_f32_16x16x32_bf16(aH[mf][kt], bL[nf], acc[mf][nf], 0, 0, 0);
                    acc[mf][nf] = __builtin_amdgcn_mfma_f32_16x16x32_bf16(aL[mf][kt], bH[nf], acc[mf][nf], 0, 0, 0);
                }
        }
        // relu + bias -> swizzled LDS (per-wave region, wave-internal ordering only)
#pragma unroll
        for (int mf = 0; mf < 2; ++mf)
#pragma unroll
            for (int nf = 0; nf < 4; ++nf)
#pragma unroll
                for (int r = 0; r < 4; ++r) {
                    int row = mf * 16 + hi16 * 4 + r;
                    int col = nf * 16 + lrow;
                    float v = fmaxf(acc[mf][nf][r] + bv[nf], 0.f);
                    *(float*)((char*)tb + ((((row << 6) + col) << 2) ^ ((row & 3) << 5))) = v;
                }
        // reload frags
#pragma unroll
        for (int mf = 0; mf < 2; ++mf)
#pragma unroll
            for (int kt = 0; kt < 2; ++kt) {
                int row = mf * 16 + lrow;
                float v[8];
                __builtin_memcpy(v, (char*)tb + ((((row << 6) + kt * 32 + koff) << 2) ^ ((row & 3) << 5)), 32);
                split8(v, aH[mf][kt], aL[mf][kt]);
            }
    }

    // ---- layer 3: 64 -> 16 (7 real) ----
    f32x4 acc3[2];
    acc3[0] = (f32x4){0.f, 0.f, 0.f, 0.f};
    acc3[1] = (f32x4){0.f, 0.f, 0.f, 0.f};
#pragma unroll
    for (int kt = 0; kt < 2; ++kt) {
        short8v bH = *((const short8v*)w3h + kt * 64 + lane);
        short8v bL = *((const short8v*)w3l + kt * 64 + lane);
#pragma unroll
        for (int mf = 0; mf < 2; ++mf) {
            acc3[mf] = __builtin_amdgcn_mfma_f32_16x16x32_bf16(aH[mf][kt], bH, acc3[mf], 0, 0, 0);
            acc3[mf] = __builtin_amdgcn_mfma_f32_16x16x32_bf16(aH[mf][kt], bL, acc3[mf], 0, 0, 0);
            acc3[mf] = __builtin_amdgcn_mfma_f32_16x16x32_bf16(aL[mf][kt], bH, acc3[mf], 0, 0, 0);
        }
    }
    // ---- log_softmax over 7 cols (lanes 0..6 of each 16-lane group) ----
#pragma unroll
    for (int mf = 0; mf < 2; ++mf)
#pragma unroll
        for (int r = 0; r < 4; ++r) {
            float z  = acc3[mf][r] + b3v;
            float zm = (lrow < NCLS) ? z : -1e30f;
            float m  = zm;
#pragma unroll
            for (int mask = 1; mask < 16; mask <<= 1)
                m = fmaxf(m, __shfl_xor(m, mask));
            float ev = (lrow < NCLS) ? expf(z - m) : 0.f;
            float ss = ev;
#pragma unroll
            for (int mask = 1; mask < 16; mask <<= 1)
                ss += __shfl_xor(ss, mask);
            float res = z - (m + logf(ss));
            int row = m0 + mf * 16 + hi16 * 4 + r;
            if (row < M && lrow < NCLS)
                out[(size_t)row * NCLS + lrow] = res;
        }
}

extern "C" void kernel_launch(void* const* d_in, const int* in_sizes, int n_in,
                              void* d_out, int out_size, void* d_ws, size_t ws_size,
                              hipStream_t stream) {
    const float* x   = (const float*)d_in[0];
    const int*   ei  = (const int*)d_in[1];
    const float* W1  = (const float*)d_in[2];
    const float* b1  = (const float*)d_in[3];
    const float* W2  = (const float*)d_in[4];
    const float* b2  = (const float*)d_in[5];
    const float* Wf1 = (const float*)d_in[6];
    const float* bf1 = (const float*)d_in[7];
    const float* Wf2 = (const float*)d_in[8];
    const float* bf2 = (const float*)d_in[9];
    const float* Wf3 = (const float*)d_in[10];
    const float* bf3 = (const float*)d_in[11];

    const int N = N_NODES;
    const int E = in_sizes[1] / 2;
    float* outp = (float*)d_out;

    char* p = (char*)d_ws;
    auto alloc = [&](size_t bytes) {
        char* q = p;
        p += (bytes + 255) & ~(size_t)255;
        return q;
    };
    int*            counts  = (int*)           alloc((size_t)N * 4);
    int*            offsets = (int*)           alloc((size_t)(N + 1) * 4);
    int*            cursor  = (int*)           alloc((size_t)N * 4);
    float*          dinv    = (float*)         alloc((size_t)N * 4);
    int*            csr_src = (int*)           alloc((size_t)E * 4);
    float*          csr_w   = (float*)         alloc((size_t)E * 4);
    unsigned short* w1fh    = (unsigned short*)alloc((size_t)NKT1 * 4 * 64 * 8 * 2);
    unsigned short* w1fl    = (unsigned short*)alloc((size_t)NKT1 * 4 * 64 * 8 * 2);
    unsigned short* w2fh    = (unsigned short*)alloc((size_t)2 * 4 * 64 * 8 * 2);
    unsigned short* w2fl    = (unsigned short*)alloc((size_t)2 * 4 * 64 * 8 * 2);
    unsigned short* wf1h    = (unsigned short*)alloc((size_t)2 * 4 * 64 * 8 * 2);
    unsigned short* wf1l    = (unsigned short*)alloc((size_t)2 * 4 * 64 * 8 * 2);
    unsigned short* wf2h    = (unsigned short*)alloc((size_t)2 * 4 * 64 * 8 * 2);
    unsigned short* wf2l    = (unsigned short*)alloc((size_t)2 * 4 * 64 * 8 * 2);
    unsigned short* wf3h    = (unsigned short*)alloc((size_t)2 * 1 * 64 * 8 * 2);
    unsigned short* wf3l    = (unsigned short*)alloc((size_t)2 * 1 * 64 * 8 * 2);
    unsigned short* bufH16  = (unsigned short*)alloc((size_t)N * HID * 2);
    float*          bufF    = (float*)         alloc((size_t)N * HID * 4);

    const int* src = ei;
    const int* dst = ei + E;

    hipMemsetAsync(counts, 0, (size_t)N * 4, stream);
    int ge = (E + 255) / 256;
    hist_kernel<<<ge, 256, 0, stream>>>(dst, counts, E);
    dinv_kernel<<<(N + 255) / 256, 256, 0, stream>>>(counts, dinv, N);
    scan_kernel<<<1, 1024, 0, stream>>>(counts, offsets, cursor, N);
    scatter_kernel<<<ge, 256, 0, stream>>>(src, dst, dinv, cursor, csr_src, csr_w, E);

    convert_wfrag_g<<<(NKT1 * 4 * 64 + 255) / 256, 256, 0, stream>>>(W1, N_FEAT, 64, NKT1, 4, w1fh, w1fl);
    convert_wfrag_g<<<2, 256, 0, stream>>>(W2, 64, 64, 2, 4, w2fh, w2fl);
    convert_wfrag_g<<<2, 256, 0, stream>>>(Wf1, 64, 64, 2, 4, wf1h, wf1l);
    convert_wfrag_g<<<2, 256, 0, stream>>>(Wf2, 64, 64, 2, 4, wf2h, wf2l);
    convert_wfrag_g<<<1, 256, 0, stream>>>(Wf3, 64, NCLS, 2, 1, wf3h, wf3l);

    // layer 1
    gemm_xw_v6<<<(N + 127) / 128, 256, 0, stream>>>(x, w1fh, w1fl, bufH16, N);
    aggregate_v2<<<(N + 3) / 4, 256, 0, stream>>>(bufH16, csr_src, csr_w, offsets, dinv, b1, bufF, N);
    // layer 2
    gemm_hid_v2<<<(N + 127) / 128, 256, 0, stream>>>(bufF, w2fh, w2fl, bufH16, N);
    aggregate_v2<<<(N + 3) / 4, 256, 0, stream>>>(bufH16, csr_src, csr_w, offsets, dinv, b2, bufF, N);
    // head
    mlp_mfma<<<(N + 127) / 128, 256, 0, stream>>>(bufF, wf1h, wf1l, wf2h, wf2l, wf3h, wf3l,
                                                  bf1, bf2, bf3, outp, N);
}

// Round 8
// 699.653 us; speedup vs baseline: 1.9244x; 1.4497x over previous
//
#include <hip/hip_runtime.h>

#define N_NODES 100000
#define N_FEAT  1433
#define NKT1    46       // k-tiles of 32 for K=1433->1472
#define HID     64
#define NCLS    7
#define SCAN_BLK 1024
#define NBLK    ((N_NODES + SCAN_BLK - 1) / SCAN_BLK)   // 98

typedef __attribute__((ext_vector_type(8))) short short8v;
typedef __attribute__((ext_vector_type(4))) float f32x4;

__device__ __forceinline__ unsigned short f2bf(float v) {
    unsigned u = __float_as_uint(v);
    unsigned r = (u + 0x7FFFu + ((u >> 16) & 1u)) >> 16;   // RNE
    return (unsigned short)r;
}
__device__ __forceinline__ float bf2f(unsigned short h) {
    return __uint_as_float(((unsigned)h) << 16);
}

// ---------------- degree histogram ----------------
__global__ __launch_bounds__(256)
void hist_kernel(const int* __restrict__ dst, int* __restrict__ counts, int E) {
    int e = blockIdx.x * 256 + threadIdx.x;
    if (e < E) atomicAdd(&counts[dst[e]], 1);
}

__global__ __launch_bounds__(256)
void dinv_kernel(const int* __restrict__ counts, float* __restrict__ dinv, int n) {
    int i = blockIdx.x * 256 + threadIdx.x;
    if (i < n) dinv[i] = rsqrtf((float)(counts[i] + 1));   // +1 = self loop
}

// ---------------- 3-phase parallel exclusive scan ----------------
__global__ __launch_bounds__(SCAN_BLK)
void scan_p1(const int* __restrict__ counts, int* __restrict__ local_ex,
             int* __restrict__ blocksum, int n) {
    __shared__ int sh[SCAN_BLK];
    int t = threadIdx.x;
    int i = blockIdx.x * SCAN_BLK + t;
    int v = (i < n) ? counts[i] : 0;
    sh[t] = v;
    __syncthreads();
    // Hillis-Steele inclusive scan
    for (int off = 1; off < SCAN_BLK; off <<= 1) {
        int u = (t >= off) ? sh[t - off] : 0;
        __syncthreads();
        sh[t] += u;
        __syncthreads();
    }
    if (i < n) local_ex[i] = sh[t] - v;      // exclusive
    if (t == SCAN_BLK - 1) blocksum[blockIdx.x] = sh[t];
}

__global__ __launch_bounds__(128)
void scan_p2(int* __restrict__ blocksum, int* __restrict__ blockoff,
             int* __restrict__ offsets_last, int nb) {
    __shared__ int sh[128];
    int t = threadIdx.x;
    int v = (t < nb) ? blocksum[t] : 0;
    sh[t] = v;
    __syncthreads();
    for (int off = 1; off < 128; off <<= 1) {
        int u = (t >= off) ? sh[t - off] : 0;
        __syncthreads();
        sh[t] += u;
        __syncthreads();
    }
    if (t < nb) blockoff[t] = sh[t] - v;
    if (t == nb - 1) *offsets_last = sh[t];   // total E' -> offsets[n]
}

__global__ __launch_bounds__(SCAN_BLK)
void scan_p3(const int* __restrict__ local_ex, const int* __restrict__ blockoff,
             int* __restrict__ offsets, int* __restrict__ cursor, int n) {
    int i = blockIdx.x * SCAN_BLK + threadIdx.x;
    if (i < n) {
        int v = local_ex[i] + blockoff[blockIdx.x];
        offsets[i] = v;
        cursor[i]  = v;
    }
}

// ---------------- CSR scatter: single int2 payload (src, weight) ----------------
__global__ __launch_bounds__(256)
void scatter_kernel(const int* __restrict__ src, const int* __restrict__ dst,
                    const float* __restrict__ dinv, int* __restrict__ cursor,
                    int2* __restrict__ pay, int E) {
    int e = blockIdx.x * 256 + threadIdx.x;
    if (e >= E) return;
    int s = src[e], d = dst[e];
    int pos = atomicAdd(&cursor[d], 1);
    pay[pos] = make_int2(s, __float_as_int(dinv[s] * dinv[d]));
}

// ---------------- generic W -> fragment-major bf16 hi/lo ----------------
__global__ __launch_bounds__(256)
void convert_wfrag_g(const float* __restrict__ W, int K, int ncols, int nkt, int nfc,
                     unsigned short* __restrict__ wfh, unsigned short* __restrict__ wfl) {
    int tid = blockIdx.x * 256 + threadIdx.x;
    if (tid >= nkt * nfc * 64) return;
    int kt   = tid / (nfc * 64);
    int rem  = tid % (nfc * 64);
    int nf   = rem >> 6;
    int lane = rem & 63;
    int n  = nf * 16 + (lane & 15);
    int kb = kt * 32 + ((lane >> 4) << 3);
    short8v hi, lo;
#pragma unroll
    for (int j = 0; j < 8; ++j) {
        int k = kb + j;
        float v = (k < K && n < ncols) ? W[(size_t)k * ncols + n] : 0.f;
        unsigned short h = f2bf(v);
        hi[j] = (short)h;
        lo[j] = (short)f2bf(v - bf2f(h));
    }
    *(short8v*)(wfh + (size_t)tid * 8) = hi;
    *(short8v*)(wfl + (size_t)tid * 8) = lo;
}

// load 8 f32 from a (4B-aligned) row, convert to bf16 fragment (masked tail path)
__device__ __forceinline__ short8v load_frag_f32(const float* __restrict__ row, int kk) {
    short8v r;
    if (kk + 8 <= N_FEAT) {
        float v[8];
        __builtin_memcpy(v, row + kk, 32);
#pragma unroll
        for (int j = 0; j < 8; ++j) r[j] = (short)f2bf(v[j]);
    } else {
#pragma unroll
        for (int j = 0; j < 8; ++j)
            r[j] = (short)((kk + j < N_FEAT) ? f2bf(row[kk + j]) : (unsigned short)0);
    }
    return r;
}

// ---------------- GEMM1 v7: W1 hi-only, 32 rows/wave, frag-major B ----------------
__global__ __launch_bounds__(256)
void gemm_xw_v7(const float* __restrict__ X,
                const unsigned short* __restrict__ wfh,
                unsigned short* __restrict__ H16, int M) {
    const int t    = threadIdx.x;
    const int lane = t & 63;
    const int w    = t >> 6;
    const int m0   = blockIdx.x * 128 + w * 32;
    const int lrow = lane & 15;
    const int koff = (lane >> 4) * 8;

    f32x4 acc[2][4];
#pragma unroll
    for (int i = 0; i < 2; ++i)
#pragma unroll
        for (int j = 0; j < 4; ++j) acc[i][j] = (f32x4){0.f, 0.f, 0.f, 0.f};

    const float* a0 = X + (size_t)min(m0 + lrow,      M - 1) * N_FEAT;
    const float* a1 = X + (size_t)min(m0 + 16 + lrow, M - 1) * N_FEAT;
    const short8v* bh = (const short8v*)wfh + lane;   // + (kt*4+nf)*64

#pragma unroll 4
    for (int kt = 0; kt < 44; ++kt) {
        int kk = kt * 32 + koff;
        short8v aH[2], bH[4];
        float v0[8], v1[8];
        __builtin_memcpy(v0, a0 + kk, 32);
        __builtin_memcpy(v1, a1 + kk, 32);
#pragma unroll
        for (int j = 0; j < 8; ++j) {
            aH[0][j] = (short)f2bf(v0[j]);
            aH[1][j] = (short)f2bf(v1[j]);
        }
#pragma unroll
        for (int nf = 0; nf < 4; ++nf)
            bH[nf] = bh[(kt * 4 + nf) * 64];
#pragma unroll
        for (int mf = 0; mf < 2; ++mf)
#pragma unroll
            for (int nf = 0; nf < 4; ++nf)
                acc[mf][nf] = __builtin_amdgcn_mfma_f32_16x16x32_bf16(aH[mf], bH[nf], acc[mf][nf], 0, 0, 0);
    }
    {   // tail kt=44 (k 1408..1439, masked >= 1433)
        const int kt = 44;
        int kk = kt * 32 + koff;
        short8v aH[2], bH[4];
        aH[0] = load_frag_f32(a0, kk);
        aH[1] = load_frag_f32(a1, kk);
#pragma unroll
        for (int nf = 0; nf < 4; ++nf)
            bH[nf] = bh[(kt * 4 + nf) * 64];
#pragma unroll
        for (int mf = 0; mf < 2; ++mf)
#pragma unroll
            for (int nf = 0; nf < 4; ++nf)
                acc[mf][nf] = __builtin_amdgcn_mfma_f32_16x16x32_bf16(aH[mf], bH[nf], acc[mf][nf], 0, 0, 0);
    }
#pragma unroll
    for (int mf = 0; mf < 2; ++mf)
#pragma unroll
        for (int r = 0; r < 4; ++r) {
            int row = m0 + mf * 16 + ((lane >> 4) << 2) + r;
            if (row < M) {
#pragma unroll
                for (int nf = 0; nf < 4; ++nf)
                    H16[(size_t)row * 64 + nf * 16 + lrow] = f2bf(acc[mf][nf][r]);
            }
        }
}

// ---------------- GEMM2 v2: [M,64] f32 @ [64,64], barrier-free, frag-major W2 hi/lo ----------------
__global__ __launch_bounds__(256)
void gemm_hid_v2(const float* __restrict__ A,
                 const unsigned short* __restrict__ wfh,
                 const unsigned short* __restrict__ wfl,
                 unsigned short* __restrict__ H16, int M) {
    const int t    = threadIdx.x;
    const int lane = t & 63;
    const int w    = t >> 6;
    const int m0   = blockIdx.x * 128 + w * 32;
    const int lrow = lane & 15;
    const int koff = (lane >> 4) * 8;

    f32x4 acc[2][4];
#pragma unroll
    for (int i = 0; i < 2; ++i)
#pragma unroll
        for (int j = 0; j < 4; ++j) acc[i][j] = (f32x4){0.f, 0.f, 0.f, 0.f};

    const float* a0 = A + (size_t)min(m0 + lrow,      M - 1) * 64;
    const float* a1 = A + (size_t)min(m0 + 16 + lrow, M - 1) * 64;
    const short8v* bh = (const short8v*)wfh + lane;
    const short8v* bl = (const short8v*)wfl + lane;

#pragma unroll
    for (int kt = 0; kt < 2; ++kt) {
        int kk = kt * 32 + koff;
        short8v aH[2], bH[4], bL[4];
        float v0[8], v1[8];
        __builtin_memcpy(v0, a0 + kk, 32);
        __builtin_memcpy(v1, a1 + kk, 32);
#pragma unroll
        for (int j = 0; j < 8; ++j) {
            aH[0][j] = (short)f2bf(v0[j]);
            aH[1][j] = (short)f2bf(v1[j]);
        }
#pragma unroll
        for (int nf = 0; nf < 4; ++nf) {
            bH[nf] = bh[(kt * 4 + nf) * 64];
            bL[nf] = bl[(kt * 4 + nf) * 64];
        }
#pragma unroll
        for (int mf = 0; mf < 2; ++mf)
#pragma unroll
            for (int nf = 0; nf < 4; ++nf) {
                acc[mf][nf] = __builtin_amdgcn_mfma_f32_16x16x32_bf16(aH[mf], bH[nf], acc[mf][nf], 0, 0, 0);
                acc[mf][nf] = __builtin_amdgcn_mfma_f32_16x16x32_bf16(aH[mf], bL[nf], acc[mf][nf], 0, 0, 0);
            }
    }
#pragma unroll
    for (int mf = 0; mf < 2; ++mf)
#pragma unroll
        for (int r = 0; r < 4; ++r) {
            int row = m0 + mf * 16 + ((lane >> 4) << 2) + r;
            if (row < M) {
#pragma unroll
                for (int nf = 0; nf < 4; ++nf)
                    H16[(size_t)row * 64 + nf * 16 + lrow] = f2bf(acc[mf][nf][r]);
            }
        }
}

// ---------------- aggregate v3: wave per node, 16-lane group per edge, int2 payload ----------------
__global__ __launch_bounds__(256)
void aggregate_v3(const unsigned short* __restrict__ h16, const int2* __restrict__ pay,
                  const int* __restrict__ offsets,
                  const float* __restrict__ dinv, const float* __restrict__ bias,
                  float* __restrict__ out, int n) {
    int wid  = (blockIdx.x * blockDim.x + threadIdx.x) >> 6;
    int lane = threadIdx.x & 63;
    if (wid >= n) return;
    const int g  = lane >> 4;          // edge subgroup 0..3
    const int f4 = (lane & 15) * 4;    // feature base

    float a0 = 0.f, a1 = 0.f, a2 = 0.f, a3 = 0.f;
    int beg = offsets[wid], end = offsets[wid + 1];
    int nq  = (end - beg) >> 2;
    int e   = beg + g;
#pragma unroll 2
    for (int q = 0; q < nq; ++q, e += 4) {
        int2  pw  = pay[e];
        float wgt = __int_as_float(pw.y);
        ushort4 hv = *(const ushort4*)(h16 + (size_t)pw.x * HID + f4);
        a0 = fmaf(bf2f(hv.x), wgt, a0);
        a1 = fmaf(bf2f(hv.y), wgt, a1);
        a2 = fmaf(bf2f(hv.z), wgt, a2);
        a3 = fmaf(bf2f(hv.w), wgt, a3);
    }
    int rem = (end - beg) & 3;
    if (g < rem) {
        int2  pw  = pay[e];
        float wgt = __int_as_float(pw.y);
        ushort4 hv = *(const ushort4*)(h16 + (size_t)pw.x * HID + f4);
        a0 = fmaf(bf2f(hv.x), wgt, a0);
        a1 = fmaf(bf2f(hv.y), wgt, a1);
        a2 = fmaf(bf2f(hv.z), wgt, a2);
        a3 = fmaf(bf2f(hv.w), wgt, a3);
    }
    if (g == 0) {   // self loop
        float di = dinv[wid];
        float w2 = di * di;
        ushort4 hv = *(const ushort4*)(h16 + (size_t)wid * HID + f4);
        a0 = fmaf(bf2f(hv.x), w2, a0);
        a1 = fmaf(bf2f(hv.y), w2, a1);
        a2 = fmaf(bf2f(hv.z), w2, a2);
        a3 = fmaf(bf2f(hv.w), w2, a3);
    }
    a0 += __shfl_xor(a0, 16); a0 += __shfl_xor(a0, 32);
    a1 += __shfl_xor(a1, 16); a1 += __shfl_xor(a1, 32);
    a2 += __shfl_xor(a2, 16); a2 += __shfl_xor(a2, 32);
    a3 += __shfl_xor(a3, 16); a3 += __shfl_xor(a3, 32);
    if (g == 0) {
        float4 bv = *(const float4*)&bias[f4];
        float4 o;
        o.x = fmaxf(a0 + bv.x, 0.f);
        o.y = fmaxf(a1 + bv.y, 0.f);
        o.z = fmaxf(a2 + bv.z, 0.f);
        o.w = fmaxf(a3 + bv.w, 0.f);
        *(float4*)&out[(size_t)wid * HID + f4] = o;
    }
}

// ---------------- fused MLP head via MFMA + butterfly log_softmax ----------------
__device__ __forceinline__ void split8(const float* v, short8v& h, short8v& l) {
#pragma unroll
    for (int j = 0; j < 8; ++j) {
        unsigned short hh = f2bf(v[j]);
        h[j] = (short)hh;
        l[j] = (short)f2bf(v[j] - bf2f(hh));
    }
}

__global__ __launch_bounds__(256)
void mlp_mfma(const float* __restrict__ y,
              const unsigned short* __restrict__ w1h, const unsigned short* __restrict__ w1l,
              const unsigned short* __restrict__ w2h, const unsigned short* __restrict__ w2l,
              const unsigned short* __restrict__ w3h, const unsigned short* __restrict__ w3l,
              const float* __restrict__ bf1, const float* __restrict__ bf2,
              const float* __restrict__ bf3,
              float* __restrict__ out, int M) {
    __shared__ float tbuf[4][32 * 64];
    const int t    = threadIdx.x;
    const int lane = t & 63;
    const int w    = t >> 6;
    const int m0   = blockIdx.x * 128 + w * 32;
    const int lrow = lane & 15;
    const int hi16 = lane >> 4;
    const int koff = hi16 * 8;
    float* tb = tbuf[w];

    float b1v[4], b2v[4];
#pragma unroll
    for (int nf = 0; nf < 4; ++nf) {
        b1v[nf] = bf1[nf * 16 + lrow];
        b2v[nf] = bf2[nf * 16 + lrow];
    }
    float b3v = (lrow < NCLS) ? bf3[lrow] : 0.f;

    short8v aH[2][2], aL[2][2];   // [mf][kt]
    {
        const float* a0 = y + (size_t)min(m0 + lrow,      M - 1) * 64;
        const float* a1 = y + (size_t)min(m0 + 16 + lrow, M - 1) * 64;
#pragma unroll
        for (int kt = 0; kt < 2; ++kt) {
            float v0[8], v1[8];
            __builtin_memcpy(v0, a0 + kt * 32 + koff, 32);
            __builtin_memcpy(v1, a1 + kt * 32 + koff, 32);
            split8(v0, aH[0][kt], aL[0][kt]);
            split8(v1, aH[1][kt], aL[1][kt]);
        }
    }

#pragma unroll
    for (int layer = 0; layer < 2; ++layer) {
        const unsigned short* wh = layer ? w2h : w1h;
        const unsigned short* wl = layer ? w2l : w1l;
        const float* bv = layer ? b2v : b1v;
        f32x4 acc[2][4];
#pragma unroll
        for (int i = 0; i < 2; ++i)
#pragma unroll
            for (int j = 0; j < 4; ++j) acc[i][j] = (f32x4){0.f, 0.f, 0.f, 0.f};
#pragma unroll
        for (int kt = 0; kt < 2; ++kt) {
            short8v bH[4], bL[4];
#pragma unroll
            for (int nf = 0; nf < 4; ++nf) {
                bH[nf] = *((const short8v*)wh + (kt * 4 + nf) * 64 + lane);
                bL[nf] = *((const short8v*)wl + (kt * 4 + nf) * 64 + lane);
            }
#pragma unroll
            for (int mf = 0; mf < 2; ++mf)
#pragma unroll
                for (int nf = 0; nf < 4; ++nf) {
                    acc[mf][nf] = __builtin_amdgcn_mfma_f32_16x16x32_bf16(aH[mf][kt], bH[nf], acc[mf][nf], 0, 0, 0);
                    acc[mf][nf] = __builtin_amdgcn_mfma_f32_16x16x32_bf16(aH[mf][kt], bL[nf], acc[mf][nf], 0, 0, 0);
                    acc[mf][nf] = __builtin_amdgcn_mfma_f32_16x16x32_bf16(aL[mf][kt], bH[nf], acc[mf][nf], 0, 0, 0);
                }
        }
#pragma unroll
        for (int mf = 0; mf < 2; ++mf)
#pragma unroll
            for (int nf = 0; nf < 4; ++nf)
#pragma unroll
                for (int r = 0; r < 4; ++r) {
                    int row = mf * 16 + hi16 * 4 + r;
                    int col = nf * 16 + lrow;
                    float v = fmaxf(acc[mf][nf][r] + bv[nf], 0.f);
                    *(float*)((char*)tb + ((((row << 6) + col) << 2) ^ ((row & 3) << 5))) = v;
                }
#pragma unroll
        for (int mf = 0; mf < 2; ++mf)
#pragma unroll
            for (int kt = 0; kt < 2; ++kt) {
                int row = mf * 16 + lrow;
                float v[8];
                __builtin_memcpy(v, (char*)tb + ((((row << 6) + kt * 32 + koff) << 2) ^ ((row & 3) << 5)), 32);
                split8(v, aH[mf][kt], aL[mf][kt]);
            }
    }

    f32x4 acc3[2];
    acc3[0] = (f32x4){0.f, 0.f, 0.f, 0.f};
    acc3[1] = (f32x4){0.f, 0.f, 0.f, 0.f};
#pragma unroll
    for (int kt = 0; kt < 2; ++kt) {
        short8v bH = *((const short8v*)w3h + kt * 64 + lane);
        short8v bL = *((const short8v*)w3l + kt * 64 + lane);
#pragma unroll
        for (int mf = 0; mf < 2; ++mf) {
            acc3[mf] = __builtin_amdgcn_mfma_f32_16x16x32_bf16(aH[mf][kt], bH, acc3[mf], 0, 0, 0);
            acc3[mf] = __builtin_amdgcn_mfma_f32_16x16x32_bf16(aH[mf][kt], bL, acc3[mf], 0, 0, 0);
            acc3[mf] = __builtin_amdgcn_mfma_f32_16x16x32_bf16(aL[mf][kt], bH, acc3[mf], 0, 0, 0);
        }
    }
#pragma unroll
    for (int mf = 0; mf < 2; ++mf)
#pragma unroll
        for (int r = 0; r < 4; ++r) {
            float z  = acc3[mf][r] + b3v;
            float zm = (lrow < NCLS) ? z : -1e30f;
            float m  = zm;
#pragma unroll
            for (int mask = 1; mask < 16; mask <<= 1)
                m = fmaxf(m, __shfl_xor(m, mask));
            float ev = (lrow < NCLS) ? expf(z - m) : 0.f;
            float ss = ev;
#pragma unroll
            for (int mask = 1; mask < 16; mask <<= 1)
                ss += __shfl_xor(ss, mask);
            float res = z - (m + logf(ss));
            int row = m0 + mf * 16 + hi16 * 4 + r;
            if (row < M && lrow < NCLS)
                out[(size_t)row * NCLS + lrow] = res;
        }
}

extern "C" void kernel_launch(void* const* d_in, const int* in_sizes, int n_in,
                              void* d_out, int out_size, void* d_ws, size_t ws_size,
                              hipStream_t stream) {
    const float* x   = (const float*)d_in[0];
    const int*   ei  = (const int*)d_in[1];
    const float* W1  = (const float*)d_in[2];
    const float* b1  = (const float*)d_in[3];
    const float* W2  = (const float*)d_in[4];
    const float* b2  = (const float*)d_in[5];
    const float* Wf1 = (const float*)d_in[6];
    const float* bf1 = (const float*)d_in[7];
    const float* Wf2 = (const float*)d_in[8];
    const float* bf2 = (const float*)d_in[9];
    const float* Wf3 = (const float*)d_in[10];
    const float* bf3 = (const float*)d_in[11];

    const int N = N_NODES;
    const int E = in_sizes[1] / 2;
    float* outp = (float*)d_out;

    char* p = (char*)d_ws;
    auto alloc = [&](size_t bytes) {
        char* q = p;
        p += (bytes + 255) & ~(size_t)255;
        return q;
    };
    int*            counts   = (int*)           alloc((size_t)N * 4);
    int*            offsets  = (int*)           alloc((size_t)(N + 1) * 4);
    int*            cursor   = (int*)           alloc((size_t)N * 4);
    int*            local_ex = (int*)           alloc((size_t)N * 4);
    int*            blocksum = (int*)           alloc((size_t)NBLK * 4);
    int*            blockoff = (int*)           alloc((size_t)NBLK * 4);
    float*          dinv     = (float*)         alloc((size_t)N * 4);
    int2*           pay      = (int2*)          alloc((size_t)E * 8);
    unsigned short* w1fh     = (unsigned short*)alloc((size_t)NKT1 * 4 * 64 * 8 * 2);
    unsigned short* w1fl     = (unsigned short*)alloc((size_t)NKT1 * 4 * 64 * 8 * 2);
    unsigned short* w2fh     = (unsigned short*)alloc((size_t)2 * 4 * 64 * 8 * 2);
    unsigned short* w2fl     = (unsigned short*)alloc((size_t)2 * 4 * 64 * 8 * 2);
    unsigned short* wf1h     = (unsigned short*)alloc((size_t)2 * 4 * 64 * 8 * 2);
    unsigned short* wf1l     = (unsigned short*)alloc((size_t)2 * 4 * 64 * 8 * 2);
    unsigned short* wf2h     = (unsigned short*)alloc((size_t)2 * 4 * 64 * 8 * 2);
    unsigned short* wf2l     = (unsigned short*)alloc((size_t)2 * 4 * 64 * 8 * 2);
    unsigned short* wf3h     = (unsigned short*)alloc((size_t)2 * 1 * 64 * 8 * 2);
    unsigned short* wf3l     = (unsigned short*)alloc((size_t)2 * 1 * 64 * 8 * 2);
    unsigned short* bufH16   = (unsigned short*)alloc((size_t)N * HID * 2);
    float*          bufF     = (float*)         alloc((size_t)N * HID * 4);

    const int* src = ei;
    const int* dst = ei + E;

    hipMemsetAsync(counts, 0, (size_t)N * 4, stream);
    int ge = (E + 255) / 256;
    hist_kernel<<<ge, 256, 0, stream>>>(dst, counts, E);
    dinv_kernel<<<(N + 255) / 256, 256, 0, stream>>>(counts, dinv, N);
    scan_p1<<<NBLK, SCAN_BLK, 0, stream>>>(counts, local_ex, blocksum, N);
    scan_p2<<<1, 128, 0, stream>>>(blocksum, blockoff, &offsets[N], NBLK);
    scan_p3<<<NBLK, SCAN_BLK, 0, stream>>>(local_ex, blockoff, offsets, cursor, N);
    scatter_kernel<<<ge, 256, 0, stream>>>(src, dst, dinv, cursor, pay, E);

    convert_wfrag_g<<<(NKT1 * 4 * 64 + 255) / 256, 256, 0, stream>>>(W1, N_FEAT, 64, NKT1, 4, w1fh, w1fl);
    convert_wfrag_g<<<2, 256, 0, stream>>>(W2, 64, 64, 2, 4, w2fh, w2fl);
    convert_wfrag_g<<<2, 256, 0, stream>>>(Wf1, 64, 64, 2, 4, wf1h, wf1l);
    convert_wfrag_g<<<2, 256, 0, stream>>>(Wf2, 64, 64, 2, 4, wf2h, wf2l);
    convert_wfrag_g<<<1, 256, 0, stream>>>(Wf3, 64, NCLS, 2, 1, wf3h, wf3l);

    // layer 1
    gemm_xw_v7<<<(N + 127) / 128, 256, 0, stream>>>(x, w1fh, bufH16, N);
    aggregate_v3<<<(N + 3) / 4, 256, 0, stream>>>(bufH16, pay, offsets, dinv, b1, bufF, N);
    // layer 2
    gemm_hid_v2<<<(N + 127) / 128, 256, 0, stream>>>(bufF, w2fh, w2fl, bufH16, N);
    aggregate_v3<<<(N + 3) / 4, 256, 0, stream>>>(bufH16, pay, offsets, dinv, b2, bufF, N);
    // head
    mlp_mfma<<<(N + 127) / 128, 256, 0, stream>>>(bufF, wf1h, wf1l, wf2h, wf2l, wf3h, wf3l,
                                                  bf1, bf2, bf3, outp, N);
}